// Round 9
// baseline (64.292 us; speedup 1.0000x reference)
//
#include <hip/hip_runtime.h>
#include <hip/hip_bf16.h>
#include <cstdint>

typedef __attribute__((ext_vector_type(4))) float f32x4;

#define DIM 256
#define TINV 10.0f
// TINV * log2(e): exp(S/T) == exp2(S * EXP2C)
#define EXP2C 14.426950408889634f
#define BM 128
#define BN 128
#define NSLOT 64   // N/BN, compile-time for full unroll in nt_reduce

// Kernel 1: row-normalize y (f32) -> fp8 e4m3 (OCP, RNE via cvt_pk); zero loss acc.
__global__ void nt_normalize(const float* __restrict__ y, uint8_t* __restrict__ ynq,
                             float* __restrict__ out, int N) {
    int tid = threadIdx.x;
    int wave = tid >> 6, lane = tid & 63;
    int row = blockIdx.x * 4 + wave;
    float4 v = ((const float4*)(y + (size_t)row * DIM))[lane];
    float ss = v.x * v.x + v.y * v.y + v.z * v.z + v.w * v.w;
#pragma unroll
    for (int off = 1; off < 64; off <<= 1) ss += __shfl_xor(ss, off);
    float inv = 1.0f / fmaxf(sqrtf(ss), 1e-8f);
    int w = __builtin_amdgcn_cvt_pk_fp8_f32(v.x * inv, v.y * inv, 0, false);
    w = __builtin_amdgcn_cvt_pk_fp8_f32(v.z * inv, v.w * inv, w, true);
    ((int*)(ynq + (size_t)row * DIM))[lane] = w;
    if (blockIdx.x == 0 && tid == 0) out[0] = 0.0f;   // zero loss accumulator
}

// Kernel 2: SINGLE-SHOT fp8 sim-GEMM + exp + partials + pos capture.
// Full K=256 strips of A and B live in LDS simultaneously (32 KB each, fp8):
// stage once -> ONE barrier -> 64 MFMAs/wave with zero mid-loop barriers/drains.
// 128x128 tile, 8 waves (2Mx4N), wave out 64x32, triangular grid (by<=bx),
// no global atomics (single-writer P), 16B-chunk XOR swizzle (rule #21).
__launch_bounds__(512, 4)
__global__ void nt_gemm(const uint8_t* __restrict__ ynq, float* __restrict__ P,
                        float* __restrict__ posterm, int N) {
    const int nt = N / BN;                      // 64
    const int T = nt * (nt + 1) / 2;            // 2080
    // bijective XCD-chunked swizzle (m204)
    int orig = blockIdx.x;
    int q = T >> 3, r = T & 7;
    int xcd = orig & 7, loc = orig >> 3;
    int t = (xcd < r ? xcd * (q + 1) : r * (q + 1) + (xcd - r) * q) + loc;
    // triangular index -> (by, bx), by <= bx (count from bottom-right corner)
    int s = T - 1 - t;
    float f = sqrtf(8.0f * (float)s + 1.0f);
    int j = (int)((f - 1.0f) * 0.5f);
    while ((j + 1) * (j + 2) / 2 <= s) ++j;
    while (j * (j + 1) / 2 > s) --j;
    int k = s - j * (j + 1) / 2;
    int by = nt - 1 - j, bx = nt - 1 - k;

    __shared__ __align__(16) uint8_t As[BM * DIM];   // 32 KB: full A strip (fp8)
    __shared__ __align__(16) uint8_t Bs[BN * DIM];   // 32 KB: full B strip (fp8)
    __shared__ float rowpart[4][BM];                 // 2 KB  [wc][row-in-tile]
    __shared__ float colpart[2][BN];                 // 1 KB  [wr][col-in-tile]

    int r0 = by * BM, c0 = bx * BN;
    int tid = threadIdx.x;
    int wave = tid >> 6, lane = tid & 63;
    int wr = wave >> 2, wc = wave & 3;               // 2 x 4 wave grid
    int l16 = lane & 15, lg = lane >> 4;

    // Stage BOTH full strips once: 2048 16B-chunks each; 512 threads x 4 iters.
    // LDS chunk (row, cc) holds global chunk (row, cc ^ (row&7)).
#pragma unroll
    for (int it = 0; it < 4; ++it) {
        int cbase = it * 512 + wave * 64;            // wave-uniform chunk base
        int c = cbase + lane;
        int row = c >> 4, cc = c & 15;               // 16 chunks per 256B row
        int gc = cc ^ (row & 7);
        const uint8_t* srcA = ynq + (size_t)(r0 + row) * DIM + gc * 16;
        __builtin_amdgcn_global_load_lds(
            (const __attribute__((address_space(1))) uint32_t*)srcA,
            (__attribute__((address_space(3))) uint32_t*)(As + cbase * 16), 16, 0, 0);
        const uint8_t* srcB = ynq + (size_t)(c0 + row) * DIM + gc * 16;
        __builtin_amdgcn_global_load_lds(
            (const __attribute__((address_space(1))) uint32_t*)srcB,
            (__attribute__((address_space(3))) uint32_t*)(Bs + cbase * 16), 16, 0, 0);
    }
    __syncthreads();   // the ONLY pre-epilogue barrier (drains staging)

    // Per-lane swizzled k-offsets: reader wants global chunk g = kk*2 + (lg>>1),
    // stored at LDS chunk g ^ (row&7); row&7 == l16&7 for every fragment row.
    int swz[8];
#pragma unroll
    for (int kk = 0; kk < 8; ++kk)
        swz[kk] = (((kk * 2 + (lg >> 1)) ^ (l16 & 7)) * 16) + (lg & 1) * 8;

    f32x4 acc[4][2] = {};
    int arow[4], brow[2];
#pragma unroll
    for (int m = 0; m < 4; ++m) arow[m] = (wr * 64 + m * 16 + l16) * DIM;
#pragma unroll
    for (int n = 0; n < 2; ++n) brow[n] = (wc * 32 + n * 16 + l16) * DIM;

#pragma unroll
    for (int kk = 0; kk < 8; ++kk) {
        long a[4], b[2];
#pragma unroll
        for (int m = 0; m < 4; ++m)
            a[m] = *(const long*)(As + arow[m] + swz[kk]);
#pragma unroll
        for (int n = 0; n < 2; ++n)
            b[n] = *(const long*)(Bs + brow[n] + swz[kk]);
#pragma unroll
        for (int m = 0; m < 4; ++m)
#pragma unroll
            for (int n = 0; n < 2; ++n)
                acc[m][n] = __builtin_amdgcn_mfma_f32_16x16x32_fp8_fp8(
                    a[m], b[n], acc[m][n], 0, 0, 0);
    }

    // Epilogue. C/D layout (m89, dtype-independent): col = lane&15, row = lg*4 + reg.
    bool diag = (by == bx);
    float colacc[2] = {0.0f, 0.0f};
#pragma unroll
    for (int m = 0; m < 4; ++m) {
#pragma unroll
        for (int r2 = 0; r2 < 4; ++r2) {
            int lrow = wr * 64 + m * 16 + lg * 4 + r2;   // row within tile
            int grow = r0 + lrow;
            float ssum = 0.0f;
#pragma unroll
            for (int n = 0; n < 2; ++n) {
                float S = acc[m][n][r2];
                float e = __builtin_amdgcn_exp2f(S * EXP2C);
                if (diag) {
                    int gcol = c0 + wc * 32 + n * 16 + l16;
                    if (gcol == grow) e = 0.0f;                        // mask diagonal
                    if (gcol == (grow ^ 1)) posterm[grow] = -S * TINV; // positive pair
                }
                ssum += e;
                colacc[n] += e;
            }
            ssum += __shfl_xor(ssum, 1);
            ssum += __shfl_xor(ssum, 2);
            ssum += __shfl_xor(ssum, 4);
            ssum += __shfl_xor(ssum, 8);
            if (l16 == 0) rowpart[wc][lrow] = ssum;
        }
    }
    // col partials: xor 16/32 reduces over this wave's 64 rows (lg groups)
#pragma unroll
    for (int n = 0; n < 2; ++n) {
        colacc[n] += __shfl_xor(colacc[n], 16);
        colacc[n] += __shfl_xor(colacc[n], 32);
    }
    if (!diag && lane < 16) {
#pragma unroll
        for (int n = 0; n < 2; ++n)
            colpart[wr][wc * 32 + n * 16 + lane] = colacc[n];
    }
    __syncthreads();
    // Single-writer stores: threads 0..127 -> row sums, 128..255 -> col sums.
    if (tid < BM) {
        P[(size_t)bx * N + r0 + tid] =
            rowpart[0][tid] + rowpart[1][tid] + rowpart[2][tid] + rowpart[3][tid];
    } else if (tid < 2 * BM && !diag) {
        int lcol = tid - BM;
        P[(size_t)by * N + c0 + lcol] = colpart[0][lcol] + colpart[1][lcol];
    }
}

// Kernel 3: loss partial = sum over NSLOT slots (compile-time, fully unrolled).
// 128 blocks x 64 threads, one row per thread; one atomicAdd per wave.
__global__ void nt_reduce(const float* __restrict__ P, const float* __restrict__ posterm,
                          float* __restrict__ out, int N) {
    int row = blockIdx.x * 64 + threadIdx.x;
    float s = 0.0f;
#pragma unroll
    for (int j = 0; j < NSLOT; ++j) s += P[(size_t)j * N + row];
    float v = posterm[row] + logf(s);
#pragma unroll
    for (int off = 1; off < 64; off <<= 1) v += __shfl_xor(v, off);
    if (threadIdx.x == 0) atomicAdd(out, v / (float)N);
}

extern "C" void kernel_launch(void* const* d_in, const int* in_sizes, int n_in,
                              void* d_out, int out_size, void* d_ws, size_t ws_size,
                              hipStream_t stream) {
    const float* y = (const float*)d_in[0];
    int N = in_sizes[0] / DIM;                 // 8192
    int nt = N / BN;                           // 64
    uint8_t* ynq = (uint8_t*)d_ws;             // N*DIM fp8 = 2 MB
    float* posterm = (float*)((char*)d_ws + (size_t)N * DIM);       // 32 KB
    float* P = posterm + N;                    // nt*N f32 = 2 MB
    float* out = (float*)d_out;

    nt_normalize<<<N / 4, 256, 0, stream>>>(y, ynq, out, N);
    int T = nt * (nt + 1) / 2;                 // 2080 blocks, no dead work
    nt_gemm<<<T, 512, 0, stream>>>(ynq, P, posterm, N);
    nt_reduce<<<N / 64, 64, 0, stream>>>(P, posterm, out, N);
}

// Round 10
// 61.278 us; speedup vs baseline: 1.0492x; 1.0492x over previous
//
#include <hip/hip_runtime.h>
#include <hip/hip_bf16.h>
#include <cstdint>

typedef __attribute__((ext_vector_type(4))) float f32x4;

#define DIM 256
#define TINV 10.0f
// TINV * log2(e): exp(S/T) == exp2(S * EXP2C)
#define EXP2C 14.426950408889634f
#define BM 128
#define BN 128
#define BK 64
#define NSLOT 64   // N/BN, compile-time for full unroll in nt_reduce

// Kernel 1: row-normalize y (f32) -> fp8 e4m3 (OCP, RNE via cvt_pk); zero loss acc.
__global__ void nt_normalize(const float* __restrict__ y, uint8_t* __restrict__ ynq,
                             float* __restrict__ out, int N) {
    int tid = threadIdx.x;
    int wave = tid >> 6, lane = tid & 63;
    int row = blockIdx.x * 4 + wave;
    float4 v = ((const float4*)(y + (size_t)row * DIM))[lane];
    float ss = v.x * v.x + v.y * v.y + v.z * v.z + v.w * v.w;
#pragma unroll
    for (int off = 1; off < 64; off <<= 1) ss += __shfl_xor(ss, off);
    float inv = 1.0f / fmaxf(sqrtf(ss), 1e-8f);
    int w = __builtin_amdgcn_cvt_pk_fp8_f32(v.x * inv, v.y * inv, 0, false);
    w = __builtin_amdgcn_cvt_pk_fp8_f32(v.z * inv, v.w * inv, w, true);
    ((int*)(ynq + (size_t)row * DIM))[lane] = w;
    if (blockIdx.x == 0 && tid == 0) out[0] = 0.0f;   // zero loss accumulator
}

// Kernel 2: fp8 sim-GEMM + exp + partials + pos capture, MAX-OCCUPANCY variant.
// 128x128 tile, 8 waves (2Mx4N, wave out 64x32), BK=64 K-loop (4 iters),
// LDS = 19 KB and VGPR<=64 => 4 blocks x 8 waves = 32 waves/CU (100%):
// barrier drains are covered by 3 co-resident blocks. Triangular grid (by<=bx),
// no global atomics (single-writer P), XOR swizzle cc^(row&3) (2-way free).
// Epilogue: butterfly reduce-scatter (15 shfl, lane l16 ends with row rid=l16).
__launch_bounds__(512, 8)
__global__ void nt_gemm(const uint8_t* __restrict__ ynq, float* __restrict__ P,
                        float* __restrict__ posterm, int N) {
    const int nt = N / BN;                      // 64
    const int T = nt * (nt + 1) / 2;            // 2080
    // bijective XCD-chunked swizzle (m204)
    int orig = blockIdx.x;
    int q = T >> 3, r = T & 7;
    int xcd = orig & 7, loc = orig >> 3;
    int t = (xcd < r ? xcd * (q + 1) : r * (q + 1) + (xcd - r) * q) + loc;
    // triangular index -> (by, bx), by <= bx (count from bottom-right corner)
    int s = T - 1 - t;
    float f = sqrtf(8.0f * (float)s + 1.0f);
    int j = (int)((f - 1.0f) * 0.5f);
    while ((j + 1) * (j + 2) / 2 <= s) ++j;
    while (j * (j + 1) / 2 > s) --j;
    int k = s - j * (j + 1) / 2;
    int by = nt - 1 - j, bx = nt - 1 - k;

    __shared__ __align__(16) uint8_t As[BM * BK];    // 8 KB (fp8 K-tile)
    __shared__ __align__(16) uint8_t Bs[BN * BK];    // 8 KB
    __shared__ float rowpart[4][BM];                 // 2 KB [wc][row-in-tile]
    __shared__ float colpart[2][BN];                 // 1 KB [wr][col-in-tile]

    int r0 = by * BM, c0 = bx * BN;
    int tid = threadIdx.x;
    int wave = tid >> 6, lane = tid & 63;
    int wr = wave >> 2, wc = wave & 3;               // 2 x 4 wave grid
    int l16 = lane & 15, lg = lane >> 4;

    // Staging: 512 chunks (16B) per matrix per K-iter; 1 chunk per thread.
    // LDS chunk (row, cc) holds global chunk (row, cc ^ (row&3)) [rule #21].
    int srow = tid >> 2, scc = tid & 3;
    int sgc = scc ^ (srow & 3);

    // Reader swizzle: global 16B chunk g = kk*2 + (lg>>1) at LDS chunk g^(row&3);
    // row&3 == l16&3 for every fragment row.
    int swz[2];
#pragma unroll
    for (int kk = 0; kk < 2; ++kk)
        swz[kk] = (((kk * 2 + (lg >> 1)) ^ (l16 & 3)) * 16) + (lg & 1) * 8;

    int arow[4], brow[2];
#pragma unroll
    for (int m = 0; m < 4; ++m) arow[m] = (wr * 64 + m * 16 + l16) * BK;
#pragma unroll
    for (int n = 0; n < 2; ++n) brow[n] = (wc * 32 + n * 16 + l16) * BK;

    f32x4 acc[4][2] = {};

    for (int k0 = 0; k0 < DIM; k0 += BK) {
        if (k0) __syncthreads();   // protect previous iter's LDS reads
        {
            const uint8_t* srcA = ynq + (size_t)(r0 + srow) * DIM + k0 + sgc * 16;
            __builtin_amdgcn_global_load_lds(
                (const __attribute__((address_space(1))) uint32_t*)srcA,
                (__attribute__((address_space(3))) uint32_t*)(As + wave * 1024), 16, 0, 0);
            const uint8_t* srcB = ynq + (size_t)(c0 + srow) * DIM + k0 + sgc * 16;
            __builtin_amdgcn_global_load_lds(
                (const __attribute__((address_space(1))) uint32_t*)srcB,
                (__attribute__((address_space(3))) uint32_t*)(Bs + wave * 1024), 16, 0, 0);
        }
        __syncthreads();   // drain; 3 co-resident blocks + 8 waves hide the stall

#pragma unroll
        for (int kk = 0; kk < 2; ++kk) {
            long a[4], b[2];
#pragma unroll
            for (int m = 0; m < 4; ++m) a[m] = *(const long*)(As + arow[m] + swz[kk]);
#pragma unroll
            for (int n = 0; n < 2; ++n) b[n] = *(const long*)(Bs + brow[n] + swz[kk]);
#pragma unroll
            for (int m = 0; m < 4; ++m)
#pragma unroll
                for (int n = 0; n < 2; ++n)
                    acc[m][n] = __builtin_amdgcn_mfma_f32_16x16x32_fp8_fp8(
                        a[m], b[n], acc[m][n], 0, 0, 0);
        }
    }

    // Epilogue. C/D layout (m89): col = lane&15, row = lg*4 + reg (within 16x16).
    bool diag = (by == bx);
    float colacc0 = 0.0f, colacc1 = 0.0f;
    float rp[16];
#pragma unroll
    for (int m = 0; m < 4; ++m) {
#pragma unroll
        for (int r2 = 0; r2 < 4; ++r2) {
            int grow = r0 + wr * 64 + m * 16 + lg * 4 + r2;
            float s0, s1;
            {
                float S = acc[m][0][r2];
                float e = __builtin_amdgcn_exp2f(S * EXP2C);
                if (diag) {
                    int gcol = c0 + wc * 32 + l16;
                    if (gcol == grow) e = 0.0f;
                    if (gcol == (grow ^ 1)) posterm[grow] = -S * TINV;
                }
                s0 = e; colacc0 += e;
            }
            {
                float S = acc[m][1][r2];
                float e = __builtin_amdgcn_exp2f(S * EXP2C);
                if (diag) {
                    int gcol = c0 + wc * 32 + 16 + l16;
                    if (gcol == grow) e = 0.0f;
                    if (gcol == (grow ^ 1)) posterm[grow] = -S * TINV;
                }
                s1 = e; colacc1 += e;
            }
            rp[m * 4 + r2] = s0 + s1;
        }
    }
    // Butterfly reduce-scatter over the 4 l16 bits: 15 shfl instead of 64.
    // After step k, surviving rid bits (below k) match l16 bits; lane l16 ends
    // holding the COMPLETE row-sum for rid = l16.
    int b0 = l16 & 1, b1 = (l16 >> 1) & 1, b2 = (l16 >> 2) & 1, b3 = (l16 >> 3) & 1;
    float t8[8];
#pragma unroll
    for (int i = 0; i < 8; ++i) {
        float send = b0 ? rp[2 * i] : rp[2 * i + 1];
        float keep = b0 ? rp[2 * i + 1] : rp[2 * i];
        t8[i] = keep + __shfl_xor(send, 1);
    }
    float t4[4];
#pragma unroll
    for (int i = 0; i < 4; ++i) {
        float send = b1 ? t8[2 * i] : t8[2 * i + 1];
        float keep = b1 ? t8[2 * i + 1] : t8[2 * i];
        t4[i] = keep + __shfl_xor(send, 2);
    }
    float t2[2];
#pragma unroll
    for (int i = 0; i < 2; ++i) {
        float send = b2 ? t4[2 * i] : t4[2 * i + 1];
        float keep = b2 ? t4[2 * i + 1] : t4[2 * i];
        t2[i] = keep + __shfl_xor(send, 4);
    }
    {
        float send = b3 ? t2[0] : t2[1];
        float keep = b3 ? t2[1] : t2[0];
        float rsum = keep + __shfl_xor(send, 8);
        int row_w = ((l16 >> 2) & 3) * 16 + lg * 4 + (l16 & 3);   // rid = l16
        rowpart[wc][wr * 64 + row_w] = rsum;                       // 1 write/lane
    }
    // col partials: xor 16/32 reduces over this wave's 64 rows (lg groups)
    colacc0 += __shfl_xor(colacc0, 16); colacc0 += __shfl_xor(colacc0, 32);
    colacc1 += __shfl_xor(colacc1, 16); colacc1 += __shfl_xor(colacc1, 32);
    if (!diag && lane < 16) {
        colpart[wr][wc * 32 + lane] = colacc0;
        colpart[wr][wc * 32 + 16 + lane] = colacc1;
    }
    __syncthreads();
    // Single-writer stores: threads 0..127 -> row sums, 128..255 -> col sums.
    if (tid < BM) {
        P[(size_t)bx * N + r0 + tid] =
            rowpart[0][tid] + rowpart[1][tid] + rowpart[2][tid] + rowpart[3][tid];
    } else if (tid < 2 * BM && !diag) {
        int lcol = tid - BM;
        P[(size_t)by * N + c0 + lcol] = colpart[0][lcol] + colpart[1][lcol];
    }
}

// Kernel 3: loss partial = sum over NSLOT slots (compile-time, fully unrolled).
// 128 blocks x 64 threads, one row per thread; one atomicAdd per wave.
__global__ void nt_reduce(const float* __restrict__ P, const float* __restrict__ posterm,
                          float* __restrict__ out, int N) {
    int row = blockIdx.x * 64 + threadIdx.x;
    float s = 0.0f;
#pragma unroll
    for (int j = 0; j < NSLOT; ++j) s += P[(size_t)j * N + row];
    float v = posterm[row] + logf(s);
#pragma unroll
    for (int off = 1; off < 64; off <<= 1) v += __shfl_xor(v, off);
    if (threadIdx.x == 0) atomicAdd(out, v / (float)N);
}

extern "C" void kernel_launch(void* const* d_in, const int* in_sizes, int n_in,
                              void* d_out, int out_size, void* d_ws, size_t ws_size,
                              hipStream_t stream) {
    const float* y = (const float*)d_in[0];
    int N = in_sizes[0] / DIM;                 // 8192
    int nt = N / BN;                           // 64
    uint8_t* ynq = (uint8_t*)d_ws;             // N*DIM fp8 = 2 MB
    float* posterm = (float*)((char*)d_ws + (size_t)N * DIM);       // 32 KB
    float* P = posterm + N;                    // nt*N f32 = 2 MB
    float* out = (float*)d_out;

    nt_normalize<<<N / 4, 256, 0, stream>>>(y, ynq, out, N);
    int T = nt * (nt + 1) / 2;                 // 2080 blocks, no dead work
    nt_gemm<<<T, 512, 0, stream>>>(ynq, P, posterm, N);
    nt_reduce<<<N / 64, 64, 0, stream>>>(P, posterm, out, N);
}